// Round 1
// baseline (548.052 us; speedup 1.0000x reference)
//
#include <hip/hip_runtime.h>

// RNN scan: B=8192 chains x T=512 steps, H=128 hidden, F=2 features.
// Per workgroup: 16 rows for all T steps; h state double-buffered in LDS (fp16).
// MFMA 16x16x32_f16, K=128 -> 4 k-chunks. Wave w owns hidden cols [32w,32w+32).
// Wave 0 additionally computes omega via an augmented B-tile (col0 = W_out),
// yielding omega_{t-1} during step t; sig2 update is one step deferred.

#define B_SZ 8192
#define T_SZ 512
#define H_SZ 128
#define ALPHA 0.2f
#define BETA 0.7f
#define R_ROWS 16
#define HS 136   // LDS row stride in halves (128 + 8 pad -> 2-way-max bank aliasing)

typedef _Float16 half8 __attribute__((ext_vector_type(8)));
typedef float floatx4 __attribute__((ext_vector_type(4)));

__global__ __launch_bounds__(256, 2)
void rnn_kernel(const float* __restrict__ x,      // (B, T, 2)
                const float* __restrict__ W_rec,  // (130, 128) rows 0..1 = x-weights
                const float* __restrict__ b_rec,  // (128)
                const float* __restrict__ W_out,  // (128, 1)
                const float* __restrict__ b_out,  // (1)
                float* __restrict__ out)          // (B)
{
    __shared__ __align__(16) _Float16 hbuf[2][R_ROWS * HS];

    const int tid   = threadIdx.x;
    const int wave  = tid >> 6;
    const int lane  = tid & 63;
    const int l15   = lane & 15;
    const int quad  = lane >> 4;
    const int rbase = blockIdx.x * R_ROWS;

    // zero initial h state (read at t=0)
    for (int i = tid; i < R_ROWS * HS; i += 256) hbuf[0][i] = (_Float16)0.f;

    // ---- load resident W_h B-fragments: B[k][n], n = l15, k = quad*8 + i ----
    const int jb = wave * 32;
    half8 Bfrag[2][4];
    for (int nt = 0; nt < 2; ++nt) {
        const int j = jb + nt * 16 + l15;
        for (int c = 0; c < 4; ++c) {
            half8 f;
            for (int i = 0; i < 8; ++i) {
                const int k = c * 32 + quad * 8 + i;
                f[i] = (_Float16)W_rec[(2 + k) * H_SZ + j];
            }
            Bfrag[nt][c] = f;
        }
    }

    // omega tile (wave 0): B col 0 = W_out, other cols 0
    half8 Ofrag[4];
    float bout = 0.f;
    if (wave == 0) {
        for (int c = 0; c < 4; ++c) {
            half8 f;
            for (int i = 0; i < 8; ++i) {
                const int k = c * 32 + quad * 8 + i;
                f[i] = (l15 == 0) ? (_Float16)W_out[k] : (_Float16)0.f;
            }
            Ofrag[c] = f;
        }
        bout = b_out[0];
    }

    // epilogue constants per n-tile: x-weights + bias for column j
    float wx0[2], wx1[2], bb[2];
    for (int nt = 0; nt < 2; ++nt) {
        const int j = jb + nt * 16 + l15;
        wx0[nt] = W_rec[0 * H_SZ + j];
        wx1[nt] = W_rec[1 * H_SZ + j];
        bb[nt]  = b_rec[j];
    }

    // x base offsets for this lane's 4 rows (rows quad*4 + reg)
    size_t xoff[4];
    for (int reg = 0; reg < 4; ++reg)
        xoff[reg] = ((size_t)(rbase + quad * 4 + reg) * T_SZ) * 2;

    float S[4]   = {0.f, 0.f, 0.f, 0.f};
    float xp[4]  = {0.f, 0.f, 0.f, 0.f};
    float xpp[4] = {0.f, 0.f, 0.f, 0.f};

    __syncthreads();

    for (int t = 0; t < T_SZ; ++t) {
        const int p = t & 1;

        // x_t for this lane's 4 rows (same addr across the 16 lanes of a quad)
        float2 xv[4];
        for (int reg = 0; reg < 4; ++reg)
            xv[reg] = *(const float2*)(x + xoff[reg] + (size_t)t * 2);

        // A-fragments of h_{t-1}: A[m][k], m = l15, k = c*32 + quad*8 + i
        half8 A[4];
        const _Float16* hb = &hbuf[p][l15 * HS + quad * 8];
        for (int c = 0; c < 4; ++c)
            A[c] = *(const half8*)(hb + c * 32);

        // main MFMAs: pre[r][j] partial = h_{t-1} @ W_h
        floatx4 acc[2];
        acc[0] = (floatx4){0.f, 0.f, 0.f, 0.f};
        acc[1] = (floatx4){0.f, 0.f, 0.f, 0.f};
        for (int c = 0; c < 4; ++c) {
            acc[0] = __builtin_amdgcn_mfma_f32_16x16x32_f16(A[c], Bfrag[0][c], acc[0], 0, 0, 0);
            acc[1] = __builtin_amdgcn_mfma_f32_16x16x32_f16(A[c], Bfrag[1][c], acc[1], 0, 0, 0);
        }

        // omega_{t-1} = h_{t-1} @ W_out (wave 0), deferred sig2 update
        if (wave == 0) {
            floatx4 oacc = {0.f, 0.f, 0.f, 0.f};
            for (int c = 0; c < 4; ++c)
                oacc = __builtin_amdgcn_mfma_f32_16x16x32_f16(A[c], Ofrag[c], oacc, 0, 0, 0);
            if (l15 == 0) {
                for (int reg = 0; reg < 4; ++reg)
                    S[reg] = S[reg] * BETA + xpp[reg] * xpp[reg] * ALPHA + oacc[reg] + bout;
            }
            for (int reg = 0; reg < 4; ++reg) { xpp[reg] = xp[reg]; xp[reg] = xv[reg].x; }
        }

        // epilogue: add x-part + bias, tanh, store h_t (fp16) to other buffer
        _Float16* hw = &hbuf[1 - p][0];
        for (int nt = 0; nt < 2; ++nt) {
            const int j = jb + nt * 16 + l15;
            for (int reg = 0; reg < 4; ++reg) {
                const float pre = acc[nt][reg] + xv[reg].x * wx0[nt] + xv[reg].y * wx1[nt] + bb[nt];
                const float e = __expf(2.f * pre);
                const float h = 1.f - 2.f / (e + 1.f);
                hw[(quad * 4 + reg) * HS + j] = (_Float16)h;
            }
        }
        __syncthreads();
    }

    // tail: omega_511 from h_511 (in hbuf[0] since T is even), final sig2
    if (wave == 0) {
        const _Float16* hb = &hbuf[0][l15 * HS + quad * 8];
        floatx4 oacc = {0.f, 0.f, 0.f, 0.f};
        for (int c = 0; c < 4; ++c) {
            half8 A = *(const half8*)(hb + c * 32);
            oacc = __builtin_amdgcn_mfma_f32_16x16x32_f16(A, Ofrag[c], oacc, 0, 0, 0);
        }
        if (l15 == 0) {
            for (int reg = 0; reg < 4; ++reg) {
                const float Sf = S[reg] * BETA + xpp[reg] * xpp[reg] * ALPHA + oacc[reg] + bout;
                out[rbase + quad * 4 + reg] = Sf;
            }
        }
    }
}

extern "C" void kernel_launch(void* const* d_in, const int* in_sizes, int n_in,
                              void* d_out, int out_size, void* d_ws, size_t ws_size,
                              hipStream_t stream) {
    const float* x     = (const float*)d_in[0];
    const float* W_rec = (const float*)d_in[1];
    const float* b_rec = (const float*)d_in[2];
    const float* W_out = (const float*)d_in[3];
    const float* b_out = (const float*)d_in[4];
    float* out = (float*)d_out;
    rnn_kernel<<<B_SZ / R_ROWS, 256, 0, stream>>>(x, W_rec, b_rec, W_out, b_out, out);
}

// Round 2
// 354.442 us; speedup vs baseline: 1.5462x; 1.5462x over previous
//
#include <hip/hip_runtime.h>

// GARCH-RNN scan: B=8192 x T=512, H=128, F=2.
// Per block: 16 rows for all T. h state double-buffered in LDS (fp16), K
// augmented to 160: row = [h(128), x0, x1, 1.0, zeros]; B-frag rows carry
// [W_h; W_x; b_rec; 0] so MFMA produces the complete pre-activation.
// sig2 recombined in closed form: sig2 = alpha*sum beta^(510-u) x_u^2
//   + (sum beta^(511-t) h_t) @ W_out + b_out/(1-beta).
// h-sum accumulated as one fma/element in the epilogue; x^2 scan is a
// one-time pre-pass; single cross-lane reduction at the end.

#define B_SZ 8192
#define T_SZ 512
#define H_SZ 128
#define ALPHA 0.2f
#define BETA 0.7f
#define R_ROWS 16
#define HS 168                 // LDS row stride in halves: 336B, 16B-aligned
#define BETA32 1.1044277e-05f  // 0.7^32
#define L2E2 2.8853900817779268f  // 2*log2(e)

typedef _Float16 half8 __attribute__((ext_vector_type(8)));
typedef float floatx4 __attribute__((ext_vector_type(4)));

__global__ __launch_bounds__(256, 2)
void rnn_kernel(const float* __restrict__ x,      // (B, T, 2)
                const float* __restrict__ W_rec,  // (130, 128)
                const float* __restrict__ b_rec,  // (128)
                const float* __restrict__ W_out,  // (128, 1)
                const float* __restrict__ b_out,  // (1)
                float* __restrict__ out)          // (B)
{
    __shared__ __align__(16) _Float16 hbuf[2][R_ROWS * HS];
    __shared__ float redS[R_ROWS][16];
    __shared__ float redO[4][R_ROWS];

    const int tid  = threadIdx.x;
    const int wave = tid >> 6, lane = tid & 63;
    const int l15  = lane & 15, quad = lane >> 4;
    const int rbase = blockIdx.x * R_ROWS;
    const int jb = wave * 32;

    // ---- one-time pre-pass: beta-weighted x^2 scan partials ----
    // Sx[row] = ALPHA * sum_{u=0}^{510} beta^(510-u) x[row,u,0]^2
    {
        const int row = tid >> 4, seg = tid & 15;
        const float* xp = x + ((size_t)(rbase + row) * T_SZ + seg * 32) * 2;
        const int n = (seg == 15) ? 31 : 32;   // exclude u=511
        float s = 0.f;
        for (int i = 0; i < n; ++i) { const float v = xp[2 * i]; s = s * BETA + v * v; }
        float w = ALPHA;
        for (int k = 0; k < 15 - seg; ++k) w *= BETA32;
        redS[row][seg] = s * w;
    }

    // ---- init LDS: zeros, then the constant-1 slot and x_0 ----
    for (int i = tid; i < R_ROWS * HS; i += 256) { hbuf[0][i] = (_Float16)0.f; hbuf[1][i] = (_Float16)0.f; }
    __syncthreads();
    if (tid < R_ROWS) {
        hbuf[0][tid * HS + 130] = (_Float16)1.f;
        hbuf[1][tid * HS + 130] = (_Float16)1.f;
    }
    const int xrow = (tid & 31) >> 1, xc = tid & 1;
    const float* xg = x + (size_t)(rbase + xrow) * T_SZ * 2 + xc;  // index by 2*t
    if (tid < 32)
        hbuf[0][xrow * HS + 128 + xc] = (_Float16)xg[0];

    // ---- resident B-fragments: 5 K-chunks x 2 n-tiles ----
    half8 Bf[5][2];
    for (int c = 0; c < 5; ++c)
        for (int nt = 0; nt < 2; ++nt) {
            const int j = jb + nt * 16 + l15;
            half8 f;
            for (int i = 0; i < 8; ++i) {
                const int k = c * 32 + quad * 8 + i;
                float v;
                if (k < 128)       v = W_rec[(2 + k) * H_SZ + j];
                else if (k == 128) v = W_rec[0 * H_SZ + j];
                else if (k == 129) v = W_rec[1 * H_SZ + j];
                else if (k == 130) v = b_rec[j];
                else               v = 0.f;
                f[i] = (_Float16)v;
            }
            Bf[c][nt] = f;
        }

    // ---- precomputed LDS pointers (both parities) ----
    const _Float16* rb[2] = { &hbuf[0][l15 * HS + quad * 8],
                              &hbuf[1][l15 * HS + quad * 8] };
    _Float16* wb[2] = { &hbuf[1][(quad * 4) * HS + jb + l15],
                        &hbuf[0][(quad * 4) * HS + jb + l15] };
    _Float16* xw[2] = { &hbuf[1][xrow * HS + 128 + xc],
                        &hbuf[0][xrow * HS + 128 + xc] };

    float Ha0[4] = {0.f, 0.f, 0.f, 0.f};
    float Ha1[4] = {0.f, 0.f, 0.f, 0.f};

    __syncthreads();

    auto step = [&](int p, int tnext, bool wx) {
        half8 A[5];
        const _Float16* r = rb[p];
        #pragma unroll
        for (int c = 0; c < 5; ++c) A[c] = *(const half8*)(r + c * 32);

        floatx4 acc0 = {0.f, 0.f, 0.f, 0.f};
        floatx4 acc1 = {0.f, 0.f, 0.f, 0.f};
        #pragma unroll
        for (int c = 0; c < 5; ++c) {
            acc0 = __builtin_amdgcn_mfma_f32_16x16x32_f16(A[c], Bf[c][0], acc0, 0, 0, 0);
            acc1 = __builtin_amdgcn_mfma_f32_16x16x32_f16(A[c], Bf[c][1], acc1, 0, 0, 0);
        }

        if (wx && tid < 32)
            *xw[p] = (_Float16)xg[2 * tnext];

        _Float16* w = wb[p];
        #pragma unroll
        for (int reg = 0; reg < 4; ++reg) {
            const float e0 = __builtin_amdgcn_exp2f(acc0[reg] * L2E2);
            const float h0 = __builtin_fmaf(-2.f, __builtin_amdgcn_rcpf(e0 + 1.f), 1.f);
            Ha0[reg] = __builtin_fmaf(Ha0[reg], BETA, h0);
            w[reg * HS + 0] = (_Float16)h0;
            const float e1 = __builtin_amdgcn_exp2f(acc1[reg] * L2E2);
            const float h1 = __builtin_fmaf(-2.f, __builtin_amdgcn_rcpf(e1 + 1.f), 1.f);
            Ha1[reg] = __builtin_fmaf(Ha1[reg], BETA, h1);
            w[reg * HS + 16] = (_Float16)h1;
        }
        __syncthreads();
    };

    for (int t = 0; t < T_SZ; t += 2) {
        step(0, t + 1, true);
        step(1, t + 2, t + 2 < T_SZ);
    }

    // ---- final: omega_total = (sum beta^k h) @ W_out, reduce, combine ----
    const float wo0 = W_out[jb + l15];
    const float wo1 = W_out[jb + 16 + l15];
    float part[4];
    #pragma unroll
    for (int reg = 0; reg < 4; ++reg)
        part[reg] = Ha0[reg] * wo0 + Ha1[reg] * wo1;
    #pragma unroll
    for (int m = 1; m < 16; m <<= 1) {
        #pragma unroll
        for (int reg = 0; reg < 4; ++reg)
            part[reg] += __shfl_xor(part[reg], m, 64);
    }
    if (l15 == 0) {
        #pragma unroll
        for (int reg = 0; reg < 4; ++reg)
            redO[wave][quad * 4 + reg] = part[reg];
    }
    __syncthreads();
    if (tid < R_ROWS) {
        const float om = redO[0][tid] + redO[1][tid] + redO[2][tid] + redO[3][tid];
        float sx = 0.f;
        for (int s = 0; s < 16; ++s) sx += redS[tid][s];
        out[rbase + tid] = om + sx + b_out[0] * (1.f / (1.f - BETA));
    }
}

extern "C" void kernel_launch(void* const* d_in, const int* in_sizes, int n_in,
                              void* d_out, int out_size, void* d_ws, size_t ws_size,
                              hipStream_t stream) {
    const float* x     = (const float*)d_in[0];
    const float* W_rec = (const float*)d_in[1];
    const float* b_rec = (const float*)d_in[2];
    const float* W_out = (const float*)d_in[3];
    const float* b_out = (const float*)d_in[4];
    float* out = (float*)d_out;
    rnn_kernel<<<B_SZ / R_ROWS, 256, 0, stream>>>(x, W_rec, b_rec, W_out, b_out, out);
}

// Round 4
// 307.188 us; speedup vs baseline: 1.7841x; 1.1538x over previous
//
#include <hip/hip_runtime.h>

// GARCH-RNN scan: B=8192 x T=512, H=128, F=2.
// Block = 16 rows x all T; h double-buffered in LDS (f16, HS=136 -> <=2-way banks).
// All x pre-staged to LDS as f16 pairs (padded stride 514 -> conflict-free);
// the step loop has ZERO global memory operations.
// K augmented to 160: chunks 0-3 = h(128); chunk 4 rows = [Wx0;Wx1;b_rec;0] with
// A4 = {x0,x1,1,0,...} (quad0 lanes only, built from one broadcast ds_read_b32).
// Weights pre-scaled by 2*log2(e) so tanh = 1 - 2*rcp(exp2(acc)+1).
// Columns paired even/odd per lane -> one cvt_pkrtz + one ds_write_b32 per pair.
// sig2 closed form: alpha*sum beta^(510-u) x_u^2 + (sum beta^(511-t) h_t)@W_out
//   + b_out/(1-beta).

#define B_SZ 8192
#define T_SZ 512
#define H_SZ 128
#define ALPHA 0.2f
#define BETA 0.7f
#define R_ROWS 16
#define HS 136                    // h row stride in halves (68 dwords = 4 mod 32)
#define XSD 514                   // x row stride in dwords (2 mod 32)
#define BETA32 1.1044277e-05f     // 0.7^32
#define L2E2 2.8853900817779268f  // 2*log2(e)

typedef _Float16 half8 __attribute__((ext_vector_type(8)));
typedef __fp16 fp16x2 __attribute__((ext_vector_type(2)));
typedef float floatx4 __attribute__((ext_vector_type(4)));
typedef unsigned int uint4v __attribute__((ext_vector_type(4)));

union H8U4 { uint4v u; half8 h; };
union U32H2 { unsigned int u; fp16x2 h; };

__global__ __launch_bounds__(256, 2)
void rnn_kernel(const float* __restrict__ x,      // (B, T, 2)
                const float* __restrict__ W_rec,  // (130, 128)
                const float* __restrict__ b_rec,  // (128)
                const float* __restrict__ W_out,  // (128, 1)
                const float* __restrict__ b_out,  // (1)
                float* __restrict__ out)          // (B)
{
    __shared__ __align__(16) _Float16 hbuf[2][R_ROWS * HS];
    __shared__ unsigned int xs[R_ROWS * XSD];   // f16 pairs {x0,x1} per (row,t)
    __shared__ float redS[R_ROWS][16];
    __shared__ float redO[4][R_ROWS];

    const int tid  = threadIdx.x;
    const int wave = tid >> 6, lane = tid & 63;
    const int l15  = lane & 15, quad = lane >> 4;
    const int rbase = blockIdx.x * R_ROWS;
    const int jb = wave * 32;

    // ---- pre-stage x -> LDS as f16 pairs (fully coalesced) ----
    {
        const float2* xg2 = (const float2*)(x + (size_t)rbase * T_SZ * 2);
        #pragma unroll 4
        for (int k = 0; k < 32; ++k) {
            const int f = tid + 256 * k;
            const float2 v = xg2[f];
            U32H2 cv; cv.h = __builtin_amdgcn_cvt_pkrtz(v.x, v.y);
            xs[(f >> 9) * XSD + (f & 511)] = cv.u;
        }
    }

    // zero initial h state (read at t=0)
    for (int i = tid; i < R_ROWS * HS; i += 256) hbuf[0][i] = (_Float16)0.f;
    __syncthreads();

    // ---- beta-weighted x^2 partials from staged x ----
    {
        const int row = tid >> 4, seg = tid & 15;
        const int base = row * XSD + seg * 32;
        const int n = (seg == 15) ? 31 : 32;   // exclude u=511
        float s = 0.f;
        for (int i = 0; i < n; ++i) {
            U32H2 cv; cv.u = xs[base + i];
            const float v = (float)cv.h[0];
            s = __builtin_fmaf(s, BETA, v * v);
        }
        float w = ALPHA;
        for (int k = 0; k < 15 - seg; ++k) w *= BETA32;
        redS[row][seg] = s * w;
    }

    // ---- resident B-fragments, columns paired even/odd, pre-scaled by L2E2 ----
    // par=0 -> col jb+2*l15, par=1 -> col jb+2*l15+1
    half8 Bf[5][2];
    for (int c = 0; c < 5; ++c)
        for (int par = 0; par < 2; ++par) {
            const int col = jb + 2 * l15 + par;
            half8 f;
            for (int i = 0; i < 8; ++i) {
                const int k = c * 32 + quad * 8 + i;
                float v;
                if (k < 128)       v = W_rec[(2 + k) * H_SZ + col];
                else if (k == 128) v = W_rec[0 * H_SZ + col];
                else if (k == 129) v = W_rec[1 * H_SZ + col];
                else if (k == 130) v = b_rec[col];
                else               v = 0.f;
                f[i] = (_Float16)(v * L2E2);
            }
            Bf[c][par] = f;
        }

    // ---- precomputed LDS pointers (both parities) ----
    const _Float16* rb[2] = { &hbuf[0][l15 * HS + quad * 8],
                              &hbuf[1][l15 * HS + quad * 8] };
    _Float16* wb[2] = { &hbuf[1][(quad * 4) * HS + jb + 2 * l15],
                        &hbuf[0][(quad * 4) * HS + jb + 2 * l15] };
    const int xbase = l15 * XSD;
    const bool q0 = (quad == 0);

    float HaE[4] = {0.f, 0.f, 0.f, 0.f};
    float HaO[4] = {0.f, 0.f, 0.f, 0.f};

    __syncthreads();

    auto step = [&](int p, int t) {
        const _Float16* r = rb[p];
        half8 A[4];
        #pragma unroll
        for (int c = 0; c < 4; ++c) A[c] = *(const half8*)(r + c * 32);

        // chunk-4 A: {x0,x1,1,0,...} on quad0 lanes, else 0 (broadcast read)
        const unsigned int xp = xs[xbase + t];
        H8U4 a4; a4.u = (uint4v){ q0 ? xp : 0u, q0 ? 0x3C00u : 0u, 0u, 0u };

        floatx4 e1 = {0.f,0.f,0.f,0.f}, e2 = {0.f,0.f,0.f,0.f};
        floatx4 o1 = {0.f,0.f,0.f,0.f}, o2 = {0.f,0.f,0.f,0.f};
        e1 = __builtin_amdgcn_mfma_f32_16x16x32_f16(A[0], Bf[0][0], e1, 0, 0, 0);
        o1 = __builtin_amdgcn_mfma_f32_16x16x32_f16(A[0], Bf[0][1], o1, 0, 0, 0);
        e2 = __builtin_amdgcn_mfma_f32_16x16x32_f16(A[1], Bf[1][0], e2, 0, 0, 0);
        o2 = __builtin_amdgcn_mfma_f32_16x16x32_f16(A[1], Bf[1][1], o2, 0, 0, 0);
        e1 = __builtin_amdgcn_mfma_f32_16x16x32_f16(A[2], Bf[2][0], e1, 0, 0, 0);
        o1 = __builtin_amdgcn_mfma_f32_16x16x32_f16(A[2], Bf[2][1], o1, 0, 0, 0);
        e2 = __builtin_amdgcn_mfma_f32_16x16x32_f16(A[3], Bf[3][0], e2, 0, 0, 0);
        o2 = __builtin_amdgcn_mfma_f32_16x16x32_f16(A[3], Bf[3][1], o2, 0, 0, 0);
        e1 = __builtin_amdgcn_mfma_f32_16x16x32_f16(a4.h, Bf[4][0], e1, 0, 0, 0);
        o1 = __builtin_amdgcn_mfma_f32_16x16x32_f16(a4.h, Bf[4][1], o1, 0, 0, 0);

        unsigned int* w = (unsigned int*)(void*)wb[p];
        #pragma unroll
        for (int reg = 0; reg < 4; ++reg) {
            const float ye = e1[reg] + e2[reg];       // = 2*log2e * pre_even
            const float yo = o1[reg] + o2[reg];
            const float he = __builtin_fmaf(-2.f,
                __builtin_amdgcn_rcpf(__builtin_amdgcn_exp2f(ye) + 1.f), 1.f);
            const float ho = __builtin_fmaf(-2.f,
                __builtin_amdgcn_rcpf(__builtin_amdgcn_exp2f(yo) + 1.f), 1.f);
            HaE[reg] = __builtin_fmaf(HaE[reg], BETA, he);
            HaO[reg] = __builtin_fmaf(HaO[reg], BETA, ho);
            U32H2 cv; cv.h = __builtin_amdgcn_cvt_pkrtz(he, ho);
            *(unsigned int*)((_Float16*)w + reg * HS) = cv.u;
        }
        __syncthreads();
    };

    for (int t = 0; t < T_SZ; t += 2) {
        step(0, t);
        step(1, t + 1);
    }

    // ---- final: omega_total = (sum beta^k h) @ W_out, reduce, combine ----
    const float woE = W_out[jb + 2 * l15];
    const float woO = W_out[jb + 2 * l15 + 1];
    float part[4];
    #pragma unroll
    for (int reg = 0; reg < 4; ++reg)
        part[reg] = HaE[reg] * woE + HaO[reg] * woO;
    #pragma unroll
    for (int m = 1; m < 16; m <<= 1) {
        #pragma unroll
        for (int reg = 0; reg < 4; ++reg)
            part[reg] += __shfl_xor(part[reg], m, 64);
    }
    if (l15 == 0) {
        #pragma unroll
        for (int reg = 0; reg < 4; ++reg)
            redO[wave][quad * 4 + reg] = part[reg];
    }
    __syncthreads();
    if (tid < R_ROWS) {
        const float om = redO[0][tid] + redO[1][tid] + redO[2][tid] + redO[3][tid];
        float sx = 0.f;
        for (int s = 0; s < 16; ++s) sx += redS[tid][s];
        out[rbase + tid] = om + sx + b_out[0] * (1.f / (1.f - BETA));
    }
}

extern "C" void kernel_launch(void* const* d_in, const int* in_sizes, int n_in,
                              void* d_out, int out_size, void* d_ws, size_t ws_size,
                              hipStream_t stream) {
    const float* x     = (const float*)d_in[0];
    const float* W_rec = (const float*)d_in[1];
    const float* b_rec = (const float*)d_in[2];
    const float* W_out = (const float*)d_in[3];
    const float* b_out = (const float*)d_in[4];
    float* out = (float*)d_out;
    rnn_kernel<<<B_SZ / R_ROWS, 256, 0, stream>>>(x, W_rec, b_rec, W_out, b_out, out);
}